// Round 1
// baseline (1140.427 us; speedup 1.0000x reference)
//
#include <hip/hip_runtime.h>
#include <math.h>

// ---------------------------------------------------------------------------
// QualityGatedMamba: x(B,T,1024) -> out(B,T,1024), f32 throughout (round 0).
// B=2, T=2048, D_MODEL=1024, D_INNER=2048, D_STATE=16, D_CONV=4, XPROJ_W=96.
// ---------------------------------------------------------------------------

constexpr int D_MODEL = 1024;
constexpr int D_STATE = 16;
constexpr int D_CONV  = 4;
constexpr int D_INNER = 2048;
constexpr int XPROJ_W = 96;          // 2*D_STATE + DT_RANK(64); only first 32 used
constexpr int B_SZ = 2, T_LEN = 2048;
constexpr int ROWS = B_SZ * T_LEN;   // 4096
constexpr int NCHUNK = 32, CHUNK = T_LEN / NCHUNK;  // 32 chunks of 64

enum { EPI_NONE = 0, EPI_DELTA = 1 };

// ---------------- GEMM: C(MxN) = A(MxK) @ B(KxN), f32, 128x128x16 tiles ----
template <int EPI>
__global__ __launch_bounds__(256)
void gemm_f32(const float* __restrict__ A, const float* __restrict__ B,
              float* __restrict__ C, int M, int N, int K,
              const float* __restrict__ bias,      // EPI_DELTA: b_delta[col]
              const float* __restrict__ sigma2,    // EPI_DELTA: per-row sigma2
              const float* __restrict__ alphap)    // EPI_DELTA: scalar alpha
{
  constexpr int BM = 128, BN = 128, BK = 16;
  __shared__ float As[BK][BM + 4];   // A^T tile (k, m), padded
  __shared__ float Bs[BK][BN];       // (k, n)

  const int tid = threadIdx.x;
  const int tx = tid & 15, ty = tid >> 4;
  const int mBase = blockIdx.y * BM;
  const int nBase = blockIdx.x * BN;

  float acc[8][8];
#pragma unroll
  for (int i = 0; i < 8; ++i)
#pragma unroll
    for (int j = 0; j < 8; ++j) acc[i][j] = 0.f;

  for (int k0 = 0; k0 < K; k0 += BK) {
    // A tile: 128 rows x 16 k  (512 float4)
#pragma unroll
    for (int l = tid; l < 512; l += 256) {
      const int row = l >> 2, kc = (l & 3) << 2;
      float4 v = *(const float4*)&A[(size_t)(mBase + row) * K + k0 + kc];
      As[kc + 0][row] = v.x; As[kc + 1][row] = v.y;
      As[kc + 2][row] = v.z; As[kc + 3][row] = v.w;
    }
    // B tile: 16 k x 128 cols (512 float4)
#pragma unroll
    for (int l = tid; l < 512; l += 256) {
      const int kr = l >> 5, nc = (l & 31) << 2;
      *(float4*)&Bs[kr][nc] =
          *(const float4*)&B[(size_t)(k0 + kr) * N + nBase + nc];
    }
    __syncthreads();
#pragma unroll
    for (int kk = 0; kk < BK; ++kk) {
      float4 a0 = *(const float4*)&As[kk][ty * 8];
      float4 a1 = *(const float4*)&As[kk][ty * 8 + 4];
      float4 b0 = *(const float4*)&Bs[kk][tx * 8];
      float4 b1 = *(const float4*)&Bs[kk][tx * 8 + 4];
      float av[8] = {a0.x, a0.y, a0.z, a0.w, a1.x, a1.y, a1.z, a1.w};
      float bv[8] = {b0.x, b0.y, b0.z, b0.w, b1.x, b1.y, b1.z, b1.w};
#pragma unroll
      for (int i = 0; i < 8; ++i)
#pragma unroll
        for (int j = 0; j < 8; ++j)
          acc[i][j] = fmaf(av[i], bv[j], acc[i][j]);
    }
    __syncthreads();
  }

  const float alphaV = (EPI == EPI_DELTA) ? alphap[0] : 0.f;
#pragma unroll
  for (int i = 0; i < 8; ++i) {
    const int r = mBase + ty * 8 + i;
    const int cb = nBase + tx * 8;
    if (EPI == EPI_DELTA) {
      const float sc = __expf(-alphaV * sigma2[r]);
#pragma unroll
      for (int j = 0; j < 8; ++j) {
        float xv = acc[i][j] + bias[cb + j];
        float sp = (xv > 20.f) ? xv : log1pf(__expf(xv));
        acc[i][j] = sp * sc;
      }
    }
    *(float4*)&C[(size_t)r * N + cb] =
        make_float4(acc[i][0], acc[i][1], acc[i][2], acc[i][3]);
    *(float4*)&C[(size_t)r * N + cb + 4] =
        make_float4(acc[i][4], acc[i][5], acc[i][6], acc[i][7]);
  }
}

// ---------------- causal depthwise conv (k=4) + SiLU ------------------------
__global__ __launch_bounds__(256)
void conv_silu_kernel(const float* __restrict__ xz, const float* __restrict__ cw,
                      const float* __restrict__ cb, float* __restrict__ u)
{
  const int idx = blockIdx.x * 256 + threadIdx.x;   // over ROWS*D_INNER
  const int c = idx & (D_INNER - 1);
  const int row = idx >> 11;
  const int t = row & (T_LEN - 1);
  const int b = row >> 11;
  float acc = cb[c];
#pragma unroll
  for (int k = 0; k < D_CONV; ++k) {
    const int tt = t + k - (D_CONV - 1);
    if (tt >= 0)
      acc = fmaf(xz[(size_t)(b * T_LEN + tt) * (2 * D_INNER) + c],
                 cw[k * D_INNER + c], acc);
  }
  u[(size_t)row * D_INNER + c] = acc / (1.f + __expf(-acc));  // SiLU
}

// ---------------- x_dbl[:, :32] = u @ W_xproj[:, :32] -----------------------
__global__ __launch_bounds__(256)
void xproj_kernel(const float* __restrict__ u, const float* __restrict__ Wx,
                  float* __restrict__ BC)
{
  const int tid = threadIdx.x;
  const int jj = tid & 31, r = tid >> 5;       // 32 cols x 8 rows per block
  const int row = blockIdx.x * 8 + r;
  const float* ur = &u[(size_t)row * D_INNER];
  float acc = 0.f;
#pragma unroll 8
  for (int k = 0; k < D_INNER; ++k)
    acc = fmaf(ur[k], Wx[(size_t)k * XPROJ_W + jj], acc);
  BC[(size_t)row * 32 + jj] = acc;
}

// ---------------- scan phase 1: per-chunk local scan (h0 = 0) ---------------
__global__ __launch_bounds__(256)
void scan1_kernel(const float* __restrict__ delta, const float* __restrict__ u,
                  const float* __restrict__ BC, const float* __restrict__ A_log,
                  float* __restrict__ hEnd, float* __restrict__ sumD)
{
  const int c = blockIdx.x * 256 + threadIdx.x;
  const int b = blockIdx.y;
  const int j = blockIdx.z;
  float a[D_STATE], h[D_STATE];
#pragma unroll
  for (int n = 0; n < D_STATE; ++n) {
    a[n] = -__expf(A_log[c * D_STATE + n]);
    h[n] = 0.f;
  }
  float sd = 0.f;
  const int t0 = j * CHUNK;
  for (int t = t0; t < t0 + CHUNK; ++t) {
    const int row = b * T_LEN + t;
    const float d = delta[(size_t)row * D_INNER + c];
    const float uu = u[(size_t)row * D_INNER + c];
    sd += d;
    const float du = d * uu;
    const float4* bp4 = (const float4*)&BC[(size_t)row * 32];
    float4 b0 = bp4[0], b1 = bp4[1], b2 = bp4[2], b3 = bp4[3];
    const float bp[16] = {b0.x, b0.y, b0.z, b0.w, b1.x, b1.y, b1.z, b1.w,
                          b2.x, b2.y, b2.z, b2.w, b3.x, b3.y, b3.z, b3.w};
#pragma unroll
    for (int n = 0; n < D_STATE; ++n)
      h[n] = fmaf(__expf(d * a[n]), h[n], du * bp[n]);
  }
  const size_t base = ((size_t)b * D_INNER + c) * NCHUNK + j;
#pragma unroll
  for (int n = 0; n < D_STATE; ++n) hEnd[base * 16 + n] = h[n];
  sumD[base] = sd;
}

// ---------------- scan phase 2: combine chunk boundaries --------------------
// hEnd is overwritten in-place with the chunk START state.
__global__ __launch_bounds__(256)
void scan2_kernel(const float* __restrict__ A_log, float* __restrict__ hEnd,
                  const float* __restrict__ sumD)
{
  const int idx = blockIdx.x * 256 + threadIdx.x;  // B*D_INNER*D_STATE = 65536
  const int n = idx & 15;
  const int c = (idx >> 4) & (D_INNER - 1);
  const int b = idx >> 15;
  const float an = -__expf(A_log[c * 16 + n]);
  float H = 0.f;
  for (int j = 0; j < NCHUNK; ++j) {
    const size_t base = ((size_t)b * D_INNER + c) * NCHUNK + j;
    const float he = hEnd[base * 16 + n];
    const float sd = sumD[base];
    hEnd[base * 16 + n] = H;                       // start state of chunk j
    H = fmaf(__expf(an * sd), H, he);
  }
}

// ---------------- scan phase 3: rescan with true h0, gate, write y ----------
// dy holds delta on entry; overwritten in-place with gated y (same element,
// read-before-write within the owning thread).
__global__ __launch_bounds__(256)
void scan3_kernel(float* dy, const float* __restrict__ u,
                  const float* __restrict__ BC, const float* __restrict__ A_log,
                  const float* __restrict__ hStart, const float* __restrict__ xz,
                  const float* __restrict__ Dp)
{
  const int c = blockIdx.x * 256 + threadIdx.x;
  const int b = blockIdx.y;
  const int j = blockIdx.z;
  float a[D_STATE], h[D_STATE];
  const size_t base = ((size_t)b * D_INNER + c) * NCHUNK + j;
#pragma unroll
  for (int n = 0; n < D_STATE; ++n) {
    a[n] = -__expf(A_log[c * D_STATE + n]);
    h[n] = hStart[base * 16 + n];
  }
  const float dpc = Dp[c];
  const int t0 = j * CHUNK;
  for (int t = t0; t < t0 + CHUNK; ++t) {
    const int row = b * T_LEN + t;
    const float d = dy[(size_t)row * D_INNER + c];
    const float uu = u[(size_t)row * D_INNER + c];
    const float du = d * uu;
    const float4* bc4 = (const float4*)&BC[(size_t)row * 32];
    float4 b0 = bc4[0], b1 = bc4[1], b2 = bc4[2], b3 = bc4[3];
    float4 c0 = bc4[4], c1 = bc4[5], c2 = bc4[6], c3 = bc4[7];
    const float bp[16] = {b0.x, b0.y, b0.z, b0.w, b1.x, b1.y, b1.z, b1.w,
                          b2.x, b2.y, b2.z, b2.w, b3.x, b3.y, b3.z, b3.w};
    const float cp[16] = {c0.x, c0.y, c0.z, c0.w, c1.x, c1.y, c1.z, c1.w,
                          c2.x, c2.y, c2.z, c2.w, c3.x, c3.y, c3.z, c3.w};
    float y = 0.f;
#pragma unroll
    for (int n = 0; n < D_STATE; ++n) {
      h[n] = fmaf(__expf(d * a[n]), h[n], du * bp[n]);
      y = fmaf(h[n], cp[n], y);
    }
    y = fmaf(uu, dpc, y);
    const float z = xz[(size_t)row * (2 * D_INNER) + D_INNER + c];
    y *= z / (1.f + __expf(-z));                   // * silu(z)
    dy[(size_t)row * D_INNER + c] = y;
  }
}

// ---------------------------------------------------------------------------
extern "C" void kernel_launch(void* const* d_in, const int* in_sizes, int n_in,
                              void* d_out, int out_size, void* d_ws,
                              size_t ws_size, hipStream_t stream)
{
  const float* x       = (const float*)d_in[0];
  const float* sigma2  = (const float*)d_in[1];
  const float* W_in    = (const float*)d_in[2];
  const float* conv_w  = (const float*)d_in[3];
  const float* conv_b  = (const float*)d_in[4];
  const float* W_xproj = (const float*)d_in[5];
  const float* W_delta = (const float*)d_in[6];
  const float* b_delta = (const float*)d_in[7];
  const float* A_log   = (const float*)d_in[8];
  const float* D_param = (const float*)d_in[9];
  const float* W_out   = (const float*)d_in[10];
  const float* alpha   = (const float*)d_in[11];
  float* out = (float*)d_out;

  char* ws = (char*)d_ws;
  float* xz   = (float*)(ws);                          // 4096x4096   64 MB
  float* u    = (float*)(ws + ((size_t)64  << 20));    // 4096x2048   32 MB
  float* dy   = (float*)(ws + ((size_t)96  << 20));    // 4096x2048   32 MB
  float* BC   = (float*)(ws + ((size_t)128 << 20));    // 4096x32    0.5 MB
  float* hEnd = (float*)(ws + ((size_t)129 << 20));    // 2*2048*32*16  8 MB
  float* sumD = (float*)(ws + ((size_t)137 << 20));    // 2*2048*32  0.5 MB

  // 1. xz = x @ W_in                     (4096 x 4096 x 1024)
  gemm_f32<EPI_NONE><<<dim3((2 * D_INNER) / 128, ROWS / 128), 256, 0, stream>>>(
      x, W_in, xz, ROWS, 2 * D_INNER, D_MODEL, nullptr, nullptr, nullptr);
  // 2. delta = softplus(x @ W_delta + b) * exp(-alpha*sigma2)
  gemm_f32<EPI_DELTA><<<dim3(D_INNER / 128, ROWS / 128), 256, 0, stream>>>(
      x, W_delta, dy, ROWS, D_INNER, D_MODEL, b_delta, sigma2, alpha);
  // 3. u = silu(causal_depthwise_conv(xz[:, :2048]))
  conv_silu_kernel<<<(ROWS * D_INNER) / 256, 256, 0, stream>>>(xz, conv_w,
                                                               conv_b, u);
  // 4. BC = u @ W_xproj[:, :32]
  xproj_kernel<<<ROWS / 8, 256, 0, stream>>>(u, W_xproj, BC);
  // 5-7. chunked diagonal scan
  scan1_kernel<<<dim3(D_INNER / 256, B_SZ, NCHUNK), 256, 0, stream>>>(
      dy, u, BC, A_log, hEnd, sumD);
  scan2_kernel<<<(B_SZ * D_INNER * D_STATE) / 256, 256, 0, stream>>>(A_log,
                                                                     hEnd, sumD);
  scan3_kernel<<<dim3(D_INNER / 256, B_SZ, NCHUNK), 256, 0, stream>>>(
      dy, u, BC, A_log, hEnd, xz, D_param);
  // 8. out = y @ W_out                   (4096 x 1024 x 2048)
  gemm_f32<EPI_NONE><<<dim3(D_MODEL / 128, ROWS / 128), 256, 0, stream>>>(
      dy, W_out, out, ROWS, D_MODEL, D_INNER, nullptr, nullptr, nullptr);
}

// Round 2
// 343.682 us; speedup vs baseline: 3.3183x; 3.3183x over previous
//
#include <hip/hip_runtime.h>
#include <math.h>

// ---------------------------------------------------------------------------
// QualityGatedMamba: x(B,T,1024) -> out(B,T,1024). Round 1: bf16 MFMA GEMMs.
// ---------------------------------------------------------------------------

constexpr int D_MODEL = 1024;
constexpr int D_STATE = 16;
constexpr int D_CONV  = 4;
constexpr int D_INNER = 2048;
constexpr int XPROJ_W = 96;          // only first 32 cols used
constexpr int B_SZ = 2, T_LEN = 2048;
constexpr int ROWS = B_SZ * T_LEN;   // 4096
constexpr int NCHUNK = 32, CHUNK = T_LEN / NCHUNK;

enum { EPI_NONE = 0, EPI_DELTA = 1 };

typedef unsigned short ushort_t;
typedef __bf16 bf16x8 __attribute__((ext_vector_type(8)));
typedef float f32x4 __attribute__((ext_vector_type(4)));

__device__ __forceinline__ ushort_t f2bf(float f) {
  unsigned int u = __float_as_uint(f);
  u = (u + 0x7fffu + ((u >> 16) & 1u)) >> 16;   // RNE (NaN not expected)
  return (ushort_t)u;
}

__device__ __forceinline__ void gload16(const void* g, void* l) {
  __builtin_amdgcn_global_load_lds(
      (const __attribute__((address_space(1))) void*)g,
      (__attribute__((address_space(3))) void*)l, 16, 0, 0);
}

// ---------------- f32 -> bf16 elementwise (x, vectorized float4) ------------
__global__ __launch_bounds__(256)
void cvt_bf16_kernel(const float* __restrict__ in, ushort_t* __restrict__ out,
                     int n4)
{
  const int i = blockIdx.x * 256 + threadIdx.x;
  if (i >= n4) return;
  const float4 v = ((const float4*)in)[i];
  ushort_t tmp[4] = {f2bf(v.x), f2bf(v.y), f2bf(v.z), f2bf(v.w)};
  ((uint2*)out)[i] = *(const uint2*)tmp;
}

// ---------------- f32 (RxC) -> bf16 transposed (CxR) ------------------------
__global__ __launch_bounds__(256)
void transpose_bf16_kernel(const float* __restrict__ in,
                           ushort_t* __restrict__ out, int R, int C)
{
  __shared__ float tile[32][33];
  const int c0 = blockIdx.x * 32, r0 = blockIdx.y * 32;
  const int tx = threadIdx.x & 31, ty = threadIdx.x >> 5;   // 32 x 8
#pragma unroll
  for (int i = 0; i < 32; i += 8)
    tile[ty + i][tx] = in[(size_t)(r0 + ty + i) * C + c0 + tx];
  __syncthreads();
#pragma unroll
  for (int i = 0; i < 32; i += 8)
    out[(size_t)(c0 + ty + i) * R + r0 + tx] = f2bf(tile[tx][ty + i]);
}

// ---------------- MFMA GEMM: C(MxN) = A(MxK) @ Bt(NxK)^T, bf16 in, f32 out --
// 128x128 tile, BK=32, 4 waves each computing 64x64 (4x4 frags of 16x16).
template <int EPI>
__global__ __launch_bounds__(256)
void gemm_mfma(const ushort_t* __restrict__ A, const ushort_t* __restrict__ Bt,
               float* __restrict__ C, int M, int N, int K,
               const float* __restrict__ bias,      // EPI_DELTA
               const float* __restrict__ sigma2,    // EPI_DELTA
               const float* __restrict__ alphap)    // EPI_DELTA
{
  __shared__ __align__(16) ushort_t As[128 * 32];
  __shared__ __align__(16) ushort_t Bs[128 * 32];
  const int tid = threadIdx.x;
  const int wave = tid >> 6, lane = tid & 63;
  const int lc = lane & 15, lr = lane >> 4;
  const int m0 = blockIdx.y * 128, n0 = blockIdx.x * 128;
  const int wm = wave >> 1, wn = wave & 1;

  f32x4 acc[4][4];
#pragma unroll
  for (int i = 0; i < 4; ++i)
#pragma unroll
    for (int j = 0; j < 4; ++j) acc[i][j] = (f32x4)0.f;

  // staging addressing: wave w covers 32 rows (2 issues of 16); lane l covers
  // row (l>>2), k-chunk (l&3)*8 -> LDS linear [row][k] with 64B rows.
  const int srow = wave * 32 + (lane >> 2);
  const int skcol = (lane & 3) * 8;
  const ushort_t* Ag = A + (size_t)(m0 + srow) * K + skcol;
  const ushort_t* Bg = Bt + (size_t)(n0 + srow) * K + skcol;
  ushort_t* AsW0 = &As[(wave * 32) * 32];
  ushort_t* AsW1 = &As[(wave * 32 + 16) * 32];
  ushort_t* BsW0 = &Bs[(wave * 32) * 32];
  ushort_t* BsW1 = &Bs[(wave * 32 + 16) * 32];

  for (int k0 = 0; k0 < K; k0 += 32) {
    if (k0) __syncthreads();
    gload16(Ag + k0, AsW0);
    gload16(Ag + k0 + (size_t)16 * K, AsW1);
    gload16(Bg + k0, BsW0);
    gload16(Bg + k0 + (size_t)16 * K, BsW1);
    __syncthreads();
    bf16x8 af[4], bfr[4];
#pragma unroll
    for (int mi = 0; mi < 4; ++mi)
      af[mi] = *(const bf16x8*)&As[(wm * 64 + mi * 16 + lc) * 32 + lr * 8];
#pragma unroll
    for (int ni = 0; ni < 4; ++ni)
      bfr[ni] = *(const bf16x8*)&Bs[(wn * 64 + ni * 16 + lc) * 32 + lr * 8];
#pragma unroll
    for (int mi = 0; mi < 4; ++mi)
#pragma unroll
      for (int ni = 0; ni < 4; ++ni)
        acc[mi][ni] = __builtin_amdgcn_mfma_f32_16x16x32_bf16(
            af[mi], bfr[ni], acc[mi][ni], 0, 0, 0);
  }

  const float alphaV = (EPI == EPI_DELTA) ? alphap[0] : 0.f;
#pragma unroll
  for (int mi = 0; mi < 4; ++mi) {
    const int rowb = m0 + wm * 64 + mi * 16 + lr * 4;
#pragma unroll
    for (int ni = 0; ni < 4; ++ni) {
      const int col = n0 + wn * 64 + ni * 16 + lc;
      f32x4 v = acc[mi][ni];
#pragma unroll
      for (int r = 0; r < 4; ++r) {
        float val = v[r];
        if (EPI == EPI_DELTA) {
          const float xv = val + bias[col];
          const float sp = (xv > 20.f) ? xv : log1pf(__expf(xv));
          val = sp * __expf(-alphaV * sigma2[rowb + r]);
        }
        C[(size_t)(rowb + r) * N + col] = val;
      }
    }
  }
}

// ---------------- causal depthwise conv (k=4) + SiLU ------------------------
__global__ __launch_bounds__(256)
void conv_silu_kernel(const float* __restrict__ xz, const float* __restrict__ cw,
                      const float* __restrict__ cb, float* __restrict__ u)
{
  const int idx = blockIdx.x * 256 + threadIdx.x;
  const int c = idx & (D_INNER - 1);
  const int row = idx >> 11;
  const int t = row & (T_LEN - 1);
  const int b = row >> 11;
  float acc = cb[c];
#pragma unroll
  for (int k = 0; k < D_CONV; ++k) {
    const int tt = t + k - (D_CONV - 1);
    if (tt >= 0)
      acc = fmaf(xz[(size_t)(b * T_LEN + tt) * (2 * D_INNER) + c],
                 cw[k * D_INNER + c], acc);
  }
  u[(size_t)row * D_INNER + c] = acc / (1.f + __expf(-acc));
}

// ---------------- BC = u @ W_xproj[:, :32] ----------------------------------
__global__ __launch_bounds__(256)
void xproj_kernel(const float* __restrict__ u, const float* __restrict__ Wx,
                  float* __restrict__ BC)
{
  const int tid = threadIdx.x;
  const int jj = tid & 31, r = tid >> 5;
  const int row = blockIdx.x * 8 + r;
  const float* ur = &u[(size_t)row * D_INNER];
  float acc = 0.f;
#pragma unroll 8
  for (int k = 0; k < D_INNER; ++k)
    acc = fmaf(ur[k], Wx[(size_t)k * XPROJ_W + jj], acc);
  BC[(size_t)row * 32 + jj] = acc;
}

// ---------------- scan phase 1 ----------------------------------------------
__global__ __launch_bounds__(256)
void scan1_kernel(const float* __restrict__ delta, const float* __restrict__ u,
                  const float* __restrict__ BC, const float* __restrict__ A_log,
                  float* __restrict__ hEnd, float* __restrict__ sumD)
{
  const int c = blockIdx.x * 256 + threadIdx.x;
  const int b = blockIdx.y;
  const int j = blockIdx.z;
  float a[D_STATE], h[D_STATE];
#pragma unroll
  for (int n = 0; n < D_STATE; ++n) {
    a[n] = -__expf(A_log[c * D_STATE + n]);
    h[n] = 0.f;
  }
  float sd = 0.f;
  const int t0 = j * CHUNK;
  for (int t = t0; t < t0 + CHUNK; ++t) {
    const int row = b * T_LEN + t;
    const float d = delta[(size_t)row * D_INNER + c];
    const float uu = u[(size_t)row * D_INNER + c];
    sd += d;
    const float du = d * uu;
    const float4* bp4 = (const float4*)&BC[(size_t)row * 32];
    float4 b0 = bp4[0], b1 = bp4[1], b2 = bp4[2], b3 = bp4[3];
    const float bp[16] = {b0.x, b0.y, b0.z, b0.w, b1.x, b1.y, b1.z, b1.w,
                          b2.x, b2.y, b2.z, b2.w, b3.x, b3.y, b3.z, b3.w};
#pragma unroll
    for (int n = 0; n < D_STATE; ++n)
      h[n] = fmaf(__expf(d * a[n]), h[n], du * bp[n]);
  }
  const size_t base = ((size_t)b * D_INNER + c) * NCHUNK + j;
#pragma unroll
  for (int n = 0; n < D_STATE; ++n) hEnd[base * 16 + n] = h[n];
  sumD[base] = sd;
}

// ---------------- scan phase 2 ----------------------------------------------
__global__ __launch_bounds__(256)
void scan2_kernel(const float* __restrict__ A_log, float* __restrict__ hEnd,
                  const float* __restrict__ sumD)
{
  const int idx = blockIdx.x * 256 + threadIdx.x;
  const int n = idx & 15;
  const int c = (idx >> 4) & (D_INNER - 1);
  const int b = idx >> 15;
  const float an = -__expf(A_log[c * 16 + n]);
  float H = 0.f;
  for (int j = 0; j < NCHUNK; ++j) {
    const size_t base = ((size_t)b * D_INNER + c) * NCHUNK + j;
    const float he = hEnd[base * 16 + n];
    const float sd = sumD[base];
    hEnd[base * 16 + n] = H;
    H = fmaf(__expf(an * sd), H, he);
  }
}

// ---------------- scan phase 3: rescan + gate, write y as bf16 --------------
__global__ __launch_bounds__(256)
void scan3_kernel(const float* __restrict__ delta, const float* __restrict__ u,
                  const float* __restrict__ BC, const float* __restrict__ A_log,
                  const float* __restrict__ hStart, const float* __restrict__ xz,
                  const float* __restrict__ Dp, ushort_t* __restrict__ yb)
{
  const int c = blockIdx.x * 256 + threadIdx.x;
  const int b = blockIdx.y;
  const int j = blockIdx.z;
  float a[D_STATE], h[D_STATE];
  const size_t base = ((size_t)b * D_INNER + c) * NCHUNK + j;
#pragma unroll
  for (int n = 0; n < D_STATE; ++n) {
    a[n] = -__expf(A_log[c * D_STATE + n]);
    h[n] = hStart[base * 16 + n];
  }
  const float dpc = Dp[c];
  const int t0 = j * CHUNK;
  for (int t = t0; t < t0 + CHUNK; ++t) {
    const int row = b * T_LEN + t;
    const float d = delta[(size_t)row * D_INNER + c];
    const float uu = u[(size_t)row * D_INNER + c];
    const float du = d * uu;
    const float4* bc4 = (const float4*)&BC[(size_t)row * 32];
    float4 b0 = bc4[0], b1 = bc4[1], b2 = bc4[2], b3 = bc4[3];
    float4 c0 = bc4[4], c1 = bc4[5], c2 = bc4[6], c3 = bc4[7];
    const float bp[16] = {b0.x, b0.y, b0.z, b0.w, b1.x, b1.y, b1.z, b1.w,
                          b2.x, b2.y, b2.z, b2.w, b3.x, b3.y, b3.z, b3.w};
    const float cp[16] = {c0.x, c0.y, c0.z, c0.w, c1.x, c1.y, c1.z, c1.w,
                          c2.x, c2.y, c2.z, c2.w, c3.x, c3.y, c3.z, c3.w};
    float y = 0.f;
#pragma unroll
    for (int n = 0; n < D_STATE; ++n) {
      h[n] = fmaf(__expf(d * a[n]), h[n], du * bp[n]);
      y = fmaf(h[n], cp[n], y);
    }
    y = fmaf(uu, dpc, y);
    const float z = xz[(size_t)row * (2 * D_INNER) + D_INNER + c];
    y *= z / (1.f + __expf(-z));
    yb[(size_t)row * D_INNER + c] = f2bf(y);
  }
}

// ---------------------------------------------------------------------------
extern "C" void kernel_launch(void* const* d_in, const int* in_sizes, int n_in,
                              void* d_out, int out_size, void* d_ws,
                              size_t ws_size, hipStream_t stream)
{
  const float* x       = (const float*)d_in[0];
  const float* sigma2  = (const float*)d_in[1];
  const float* W_in    = (const float*)d_in[2];
  const float* conv_w  = (const float*)d_in[3];
  const float* conv_b  = (const float*)d_in[4];
  const float* W_xproj = (const float*)d_in[5];
  const float* W_delta = (const float*)d_in[6];
  const float* b_delta = (const float*)d_in[7];
  const float* A_log   = (const float*)d_in[8];
  const float* D_param = (const float*)d_in[9];
  const float* W_out   = (const float*)d_in[10];
  const float* alpha   = (const float*)d_in[11];
  float* out = (float*)d_out;

  char* ws = (char*)d_ws;
  float*    xz   = (float*)(ws);                          //  0-64MB
  float*    u    = (float*)(ws + ((size_t)64  << 20));    //  64-96
  float*    dy   = (float*)(ws + ((size_t)96  << 20));    //  96-128 (delta)
  float*    BC   = (float*)(ws + ((size_t)128 << 20));    // 128-128.5
  float*    hEnd = (float*)(ws + ((size_t)129 << 20));    // 129-137
  float*    sumD = (float*)(ws + ((size_t)137 << 20));    // 137-137.5
  ushort_t* xb   = (ushort_t*)(ws + ((size_t)138 << 20)); // 138-146 (x bf16)
  ushort_t* WiT  = (ushort_t*)(ws + ((size_t)146 << 20)); // 146-154 (4096x1024)
  ushort_t* WdT  = (ushort_t*)(ws + ((size_t)154 << 20)); // 154-158 (2048x1024)
  ushort_t* WoT  = (ushort_t*)(ws + ((size_t)158 << 20)); // 158-162 (1024x2048)
  ushort_t* yb   = (ushort_t*)(ws + ((size_t)162 << 20)); // 162-178 (4096x2048)

  // 0. conversions
  cvt_bf16_kernel<<<(ROWS * D_MODEL / 4) / 256, 256, 0, stream>>>(
      x, xb, ROWS * D_MODEL / 4);
  transpose_bf16_kernel<<<dim3(2 * D_INNER / 32, D_MODEL / 32), 256, 0,
                          stream>>>(W_in, WiT, D_MODEL, 2 * D_INNER);
  transpose_bf16_kernel<<<dim3(D_INNER / 32, D_MODEL / 32), 256, 0, stream>>>(
      W_delta, WdT, D_MODEL, D_INNER);
  transpose_bf16_kernel<<<dim3(D_MODEL / 32, D_INNER / 32), 256, 0, stream>>>(
      W_out, WoT, D_INNER, D_MODEL);

  // 1. xz = x @ W_in
  gemm_mfma<EPI_NONE><<<dim3((2 * D_INNER) / 128, ROWS / 128), 256, 0,
                        stream>>>(xb, WiT, xz, ROWS, 2 * D_INNER, D_MODEL,
                                  nullptr, nullptr, nullptr);
  // 2. delta = softplus(x @ W_delta + b) * exp(-alpha*sigma2)
  gemm_mfma<EPI_DELTA><<<dim3(D_INNER / 128, ROWS / 128), 256, 0, stream>>>(
      xb, WdT, dy, ROWS, D_INNER, D_MODEL, b_delta, sigma2, alpha);
  // 3. u = silu(conv(xz[:, :2048]))
  conv_silu_kernel<<<(ROWS * D_INNER) / 256, 256, 0, stream>>>(xz, conv_w,
                                                               conv_b, u);
  // 4. BC = u @ W_xproj[:, :32]
  xproj_kernel<<<ROWS / 8, 256, 0, stream>>>(u, W_xproj, BC);
  // 5-7. chunked scan
  scan1_kernel<<<dim3(D_INNER / 256, B_SZ, NCHUNK), 256, 0, stream>>>(
      dy, u, BC, A_log, hEnd, sumD);
  scan2_kernel<<<(B_SZ * D_INNER * D_STATE) / 256, 256, 0, stream>>>(A_log,
                                                                     hEnd, sumD);
  scan3_kernel<<<dim3(D_INNER / 256, B_SZ, NCHUNK), 256, 0, stream>>>(
      dy, u, BC, A_log, hEnd, xz, D_param, yb);
  // 8. out = y @ W_out
  gemm_mfma<EPI_NONE><<<dim3(D_MODEL / 128, ROWS / 128), 256, 0, stream>>>(
      yb, WoT, out, ROWS, D_MODEL, D_INNER, nullptr, nullptr, nullptr);
}

// Round 3
// 280.196 us; speedup vs baseline: 4.0701x; 1.2266x over previous
//
#include <hip/hip_runtime.h>
#include <math.h>

// ---------------------------------------------------------------------------
// QualityGatedMamba: x(B,T,1024) -> out(B,T,1024). Round 2: fused conv+xproj.
// ---------------------------------------------------------------------------

constexpr int D_MODEL = 1024;
constexpr int D_STATE = 16;
constexpr int D_CONV  = 4;
constexpr int D_INNER = 2048;
constexpr int XPROJ_W = 96;          // only first 32 cols used
constexpr int B_SZ = 2, T_LEN = 2048;
constexpr int ROWS = B_SZ * T_LEN;   // 4096
constexpr int NCHUNK = 32, CHUNK = T_LEN / NCHUNK;

enum { EPI_NONE = 0, EPI_DELTA = 1 };

typedef unsigned short ushort_t;
typedef __bf16 bf16x8 __attribute__((ext_vector_type(8)));
typedef float f32x4 __attribute__((ext_vector_type(4)));

__device__ __forceinline__ ushort_t f2bf(float f) {
  unsigned int u = __float_as_uint(f);
  u = (u + 0x7fffu + ((u >> 16) & 1u)) >> 16;   // RNE
  return (ushort_t)u;
}

__device__ __forceinline__ void gload16(const void* g, void* l) {
  __builtin_amdgcn_global_load_lds(
      (const __attribute__((address_space(1))) void*)g,
      (__attribute__((address_space(3))) void*)l, 16, 0, 0);
}

// ---------------- f32 -> bf16 elementwise -----------------------------------
__global__ __launch_bounds__(256)
void cvt_bf16_kernel(const float* __restrict__ in, ushort_t* __restrict__ out,
                     int n4)
{
  const int i = blockIdx.x * 256 + threadIdx.x;
  if (i >= n4) return;
  const float4 v = ((const float4*)in)[i];
  ushort_t tmp[4] = {f2bf(v.x), f2bf(v.y), f2bf(v.z), f2bf(v.w)};
  ((uint2*)out)[i] = *(const uint2*)tmp;
}

// ---------------- f32 (RxC) -> bf16 transposed (CxR) ------------------------
__global__ __launch_bounds__(256)
void transpose_bf16_kernel(const float* __restrict__ in,
                           ushort_t* __restrict__ out, int R, int C)
{
  __shared__ float tile[32][33];
  const int c0 = blockIdx.x * 32, r0 = blockIdx.y * 32;
  const int tx = threadIdx.x & 31, ty = threadIdx.x >> 5;   // 32 x 8
#pragma unroll
  for (int i = 0; i < 32; i += 8)
    tile[ty + i][tx] = in[(size_t)(r0 + ty + i) * C + c0 + tx];
  __syncthreads();
#pragma unroll
  for (int i = 0; i < 32; i += 8)
    out[(size_t)(c0 + ty + i) * R + r0 + tx] = f2bf(tile[tx][ty + i]);
}

// ---------------- MFMA GEMM: C(MxN) = A(MxK) @ Bt(NxK)^T --------------------
template <int EPI>
__global__ __launch_bounds__(256)
void gemm_mfma(const ushort_t* __restrict__ A, const ushort_t* __restrict__ Bt,
               float* __restrict__ C, int M, int N, int K,
               const float* __restrict__ bias,
               const float* __restrict__ sigma2,
               const float* __restrict__ alphap)
{
  __shared__ __align__(16) ushort_t As[128 * 32];
  __shared__ __align__(16) ushort_t Bs[128 * 32];
  const int tid = threadIdx.x;
  const int wave = tid >> 6, lane = tid & 63;
  const int lc = lane & 15, lr = lane >> 4;
  const int m0 = blockIdx.y * 128, n0 = blockIdx.x * 128;
  const int wm = wave >> 1, wn = wave & 1;

  f32x4 acc[4][4];
#pragma unroll
  for (int i = 0; i < 4; ++i)
#pragma unroll
    for (int j = 0; j < 4; ++j) acc[i][j] = (f32x4)0.f;

  const int srow = wave * 32 + (lane >> 2);
  const int skcol = (lane & 3) * 8;
  const ushort_t* Ag = A + (size_t)(m0 + srow) * K + skcol;
  const ushort_t* Bg = Bt + (size_t)(n0 + srow) * K + skcol;
  ushort_t* AsW0 = &As[(wave * 32) * 32];
  ushort_t* AsW1 = &As[(wave * 32 + 16) * 32];
  ushort_t* BsW0 = &Bs[(wave * 32) * 32];
  ushort_t* BsW1 = &Bs[(wave * 32 + 16) * 32];

  for (int k0 = 0; k0 < K; k0 += 32) {
    if (k0) __syncthreads();
    gload16(Ag + k0, AsW0);
    gload16(Ag + k0 + (size_t)16 * K, AsW1);
    gload16(Bg + k0, BsW0);
    gload16(Bg + k0 + (size_t)16 * K, BsW1);
    __syncthreads();
    bf16x8 af[4], bfr[4];
#pragma unroll
    for (int mi = 0; mi < 4; ++mi)
      af[mi] = *(const bf16x8*)&As[(wm * 64 + mi * 16 + lc) * 32 + lr * 8];
#pragma unroll
    for (int ni = 0; ni < 4; ++ni)
      bfr[ni] = *(const bf16x8*)&Bs[(wn * 64 + ni * 16 + lc) * 32 + lr * 8];
#pragma unroll
    for (int mi = 0; mi < 4; ++mi)
#pragma unroll
      for (int ni = 0; ni < 4; ++ni)
        acc[mi][ni] = __builtin_amdgcn_mfma_f32_16x16x32_bf16(
            af[mi], bfr[ni], acc[mi][ni], 0, 0, 0);
  }

  const float alphaV = (EPI == EPI_DELTA) ? alphap[0] : 0.f;
#pragma unroll
  for (int mi = 0; mi < 4; ++mi) {
    const int rowb = m0 + wm * 64 + mi * 16 + lr * 4;
#pragma unroll
    for (int ni = 0; ni < 4; ++ni) {
      const int col = n0 + wn * 64 + ni * 16 + lc;
      f32x4 v = acc[mi][ni];
#pragma unroll
      for (int r = 0; r < 4; ++r) {
        float val = v[r];
        if (EPI == EPI_DELTA) {
          const float xv = val + bias[col];
          const float sp = (xv > 20.f) ? xv : log1pf(__expf(xv));
          val = sp * __expf(-alphaV * sigma2[rowb + r]);
        }
        C[(size_t)(rowb + r) * N + col] = val;
      }
    }
  }
}

// ---------------- fused conv(k=4)+SiLU+xproj, 8 rows per block --------------
__global__ __launch_bounds__(256)
void conv_xproj_kernel(const float* __restrict__ xz, const float* __restrict__ cw,
                       const float* __restrict__ cb, const float* __restrict__ Wx,
                       float* __restrict__ u, float* __restrict__ BC)
{
  __shared__ float us[8][D_INNER];          // 64 KB
  __shared__ float red[8][8][32];           //  8 KB
  const int tid = threadIdx.x;
  const int b = blockIdx.y;
  const int t0 = blockIdx.x * 8;
  const float4* xz4 = (const float4*)xz;
  const float4* cw4 = (const float4*)cw;
  const float4* cb4 = (const float4*)cb;
  float4* u4g = (float4*)u;

#pragma unroll
  for (int q = 0; q < 2; ++q) {
    const int c4 = tid + q * 256;           // float4 channel index 0..511
    float4 wt[4];
#pragma unroll
    for (int k = 0; k < 4; ++k) wt[k] = cw4[k * 512 + c4];
    const float4 bias = cb4[c4];
#pragma unroll
    for (int r = 0; r < 8; ++r) {
      const int t = t0 + r;
      float4 acc = bias;
#pragma unroll
      for (int k = 0; k < 4; ++k) {
        const int tt = t + k - 3;
        if (tt >= 0) {
          const float4 v = xz4[(size_t)(b * T_LEN + tt) * 1024 + c4];
          acc.x = fmaf(v.x, wt[k].x, acc.x);
          acc.y = fmaf(v.y, wt[k].y, acc.y);
          acc.z = fmaf(v.z, wt[k].z, acc.z);
          acc.w = fmaf(v.w, wt[k].w, acc.w);
        }
      }
      acc.x = acc.x / (1.f + __expf(-acc.x));
      acc.y = acc.y / (1.f + __expf(-acc.y));
      acc.z = acc.z / (1.f + __expf(-acc.z));
      acc.w = acc.w / (1.f + __expf(-acc.w));
      u4g[(size_t)(b * T_LEN + t) * 512 + c4] = acc;
      *(float4*)&us[r][c4 * 4] = acc;
    }
  }
  __syncthreads();

  const int j = tid & 31, chunk = tid >> 5;
  float p[8] = {0.f, 0.f, 0.f, 0.f, 0.f, 0.f, 0.f, 0.f};
  const float* WxC = Wx + j;
  for (int i = 0; i < 256; ++i) {
    const int k = chunk * 256 + i;
    const float w = WxC[(size_t)k * XPROJ_W];
#pragma unroll
    for (int r = 0; r < 8; ++r) p[r] = fmaf(us[r][k], w, p[r]);
  }
#pragma unroll
  for (int r = 0; r < 8; ++r) red[r][chunk][j] = p[r];
  __syncthreads();
  {
    const int r = tid >> 5, jj = tid & 31;
    float s = 0.f;
#pragma unroll
    for (int c = 0; c < 8; ++c) s += red[r][c][jj];
    BC[(size_t)(b * T_LEN + t0 + r) * 32 + jj] = s;
  }
}

// ---------------- scan phase 1 ----------------------------------------------
__global__ __launch_bounds__(256)
void scan1_kernel(const float* __restrict__ delta, const float* __restrict__ u,
                  const float* __restrict__ BC, const float* __restrict__ A_log,
                  float* __restrict__ hEnd, float* __restrict__ sumD)
{
  const int c = blockIdx.x * 256 + threadIdx.x;
  const int b = blockIdx.y;
  const int j = blockIdx.z;
  float a[D_STATE], h[D_STATE];
#pragma unroll
  for (int n = 0; n < D_STATE; ++n) {
    a[n] = -__expf(A_log[c * D_STATE + n]);
    h[n] = 0.f;
  }
  float sd = 0.f;
  const int t0 = j * CHUNK;
  for (int t = t0; t < t0 + CHUNK; ++t) {
    const int row = b * T_LEN + t;
    const float d = delta[(size_t)row * D_INNER + c];
    const float uu = u[(size_t)row * D_INNER + c];
    sd += d;
    const float du = d * uu;
    const float4* bp4 = (const float4*)&BC[(size_t)row * 32];
    float4 b0 = bp4[0], b1 = bp4[1], b2 = bp4[2], b3 = bp4[3];
    const float bp[16] = {b0.x, b0.y, b0.z, b0.w, b1.x, b1.y, b1.z, b1.w,
                          b2.x, b2.y, b2.z, b2.w, b3.x, b3.y, b3.z, b3.w};
#pragma unroll
    for (int n = 0; n < D_STATE; ++n)
      h[n] = fmaf(__expf(d * a[n]), h[n], du * bp[n]);
  }
  const size_t base = ((size_t)b * D_INNER + c) * NCHUNK + j;
#pragma unroll
  for (int n = 0; n < D_STATE; ++n) hEnd[base * 16 + n] = h[n];
  sumD[base] = sd;
}

// ---------------- scan phase 2 ----------------------------------------------
__global__ __launch_bounds__(256)
void scan2_kernel(const float* __restrict__ A_log, float* __restrict__ hEnd,
                  const float* __restrict__ sumD)
{
  const int idx = blockIdx.x * 256 + threadIdx.x;
  const int n = idx & 15;
  const int c = (idx >> 4) & (D_INNER - 1);
  const int b = idx >> 15;
  const float an = -__expf(A_log[c * 16 + n]);
  float H = 0.f;
  for (int j = 0; j < NCHUNK; ++j) {
    const size_t base = ((size_t)b * D_INNER + c) * NCHUNK + j;
    const float he = hEnd[base * 16 + n];
    const float sd = sumD[base];
    hEnd[base * 16 + n] = H;
    H = fmaf(__expf(an * sd), H, he);
  }
}

// ---------------- scan phase 3: rescan + gate, write y as bf16 --------------
__global__ __launch_bounds__(256)
void scan3_kernel(const float* __restrict__ delta, const float* __restrict__ u,
                  const float* __restrict__ BC, const float* __restrict__ A_log,
                  const float* __restrict__ hStart, const float* __restrict__ xz,
                  const float* __restrict__ Dp, ushort_t* __restrict__ yb)
{
  const int c = blockIdx.x * 256 + threadIdx.x;
  const int b = blockIdx.y;
  const int j = blockIdx.z;
  float a[D_STATE], h[D_STATE];
  const size_t base = ((size_t)b * D_INNER + c) * NCHUNK + j;
#pragma unroll
  for (int n = 0; n < D_STATE; ++n) {
    a[n] = -__expf(A_log[c * D_STATE + n]);
    h[n] = hStart[base * 16 + n];
  }
  const float dpc = Dp[c];
  const int t0 = j * CHUNK;
  for (int t = t0; t < t0 + CHUNK; ++t) {
    const int row = b * T_LEN + t;
    const float d = delta[(size_t)row * D_INNER + c];
    const float uu = u[(size_t)row * D_INNER + c];
    const float du = d * uu;
    const float4* bc4 = (const float4*)&BC[(size_t)row * 32];
    float4 b0 = bc4[0], b1 = bc4[1], b2 = bc4[2], b3 = bc4[3];
    float4 c0 = bc4[4], c1 = bc4[5], c2 = bc4[6], c3 = bc4[7];
    const float bp[16] = {b0.x, b0.y, b0.z, b0.w, b1.x, b1.y, b1.z, b1.w,
                          b2.x, b2.y, b2.z, b2.w, b3.x, b3.y, b3.z, b3.w};
    const float cp[16] = {c0.x, c0.y, c0.z, c0.w, c1.x, c1.y, c1.z, c1.w,
                          c2.x, c2.y, c2.z, c2.w, c3.x, c3.y, c3.z, c3.w};
    float y = 0.f;
#pragma unroll
    for (int n = 0; n < D_STATE; ++n) {
      h[n] = fmaf(__expf(d * a[n]), h[n], du * bp[n]);
      y = fmaf(h[n], cp[n], y);
    }
    y = fmaf(uu, dpc, y);
    const float z = xz[(size_t)row * (2 * D_INNER) + D_INNER + c];
    y *= z / (1.f + __expf(-z));
    yb[(size_t)row * D_INNER + c] = f2bf(y);
  }
}

// ---------------------------------------------------------------------------
extern "C" void kernel_launch(void* const* d_in, const int* in_sizes, int n_in,
                              void* d_out, int out_size, void* d_ws,
                              size_t ws_size, hipStream_t stream)
{
  const float* x       = (const float*)d_in[0];
  const float* sigma2  = (const float*)d_in[1];
  const float* W_in    = (const float*)d_in[2];
  const float* conv_w  = (const float*)d_in[3];
  const float* conv_b  = (const float*)d_in[4];
  const float* W_xproj = (const float*)d_in[5];
  const float* W_delta = (const float*)d_in[6];
  const float* b_delta = (const float*)d_in[7];
  const float* A_log   = (const float*)d_in[8];
  const float* D_param = (const float*)d_in[9];
  const float* W_out   = (const float*)d_in[10];
  const float* alpha   = (const float*)d_in[11];
  float* out = (float*)d_out;

  char* ws = (char*)d_ws;
  float*    xz   = (float*)(ws);                          //  0-64MB
  float*    u    = (float*)(ws + ((size_t)64  << 20));    //  64-96
  float*    dy   = (float*)(ws + ((size_t)96  << 20));    //  96-128 (delta)
  float*    BC   = (float*)(ws + ((size_t)128 << 20));    // 128-128.5
  float*    hEnd = (float*)(ws + ((size_t)129 << 20));    // 129-137
  float*    sumD = (float*)(ws + ((size_t)137 << 20));    // 137-137.5
  ushort_t* xb   = (ushort_t*)(ws + ((size_t)138 << 20)); // 138-146
  ushort_t* WiT  = (ushort_t*)(ws + ((size_t)146 << 20)); // 146-154
  ushort_t* WdT  = (ushort_t*)(ws + ((size_t)154 << 20)); // 154-158
  ushort_t* WoT  = (ushort_t*)(ws + ((size_t)158 << 20)); // 158-162
  ushort_t* yb   = (ushort_t*)(ws + ((size_t)162 << 20)); // 162-178

  // 0. conversions
  cvt_bf16_kernel<<<(ROWS * D_MODEL / 4) / 256, 256, 0, stream>>>(
      x, xb, ROWS * D_MODEL / 4);
  transpose_bf16_kernel<<<dim3(2 * D_INNER / 32, D_MODEL / 32), 256, 0,
                          stream>>>(W_in, WiT, D_MODEL, 2 * D_INNER);
  transpose_bf16_kernel<<<dim3(D_INNER / 32, D_MODEL / 32), 256, 0, stream>>>(
      W_delta, WdT, D_MODEL, D_INNER);
  transpose_bf16_kernel<<<dim3(D_MODEL / 32, D_INNER / 32), 256, 0, stream>>>(
      W_out, WoT, D_INNER, D_MODEL);

  // 1. xz = x @ W_in
  gemm_mfma<EPI_NONE><<<dim3((2 * D_INNER) / 128, ROWS / 128), 256, 0,
                        stream>>>(xb, WiT, xz, ROWS, 2 * D_INNER, D_MODEL,
                                  nullptr, nullptr, nullptr);
  // 2. delta = softplus(x @ W_delta + b) * exp(-alpha*sigma2)
  gemm_mfma<EPI_DELTA><<<dim3(D_INNER / 128, ROWS / 128), 256, 0, stream>>>(
      xb, WdT, dy, ROWS, D_INNER, D_MODEL, b_delta, sigma2, alpha);
  // 3+4. u = silu(conv(xz[:, :2048])); BC = u @ W_xproj[:, :32]
  conv_xproj_kernel<<<dim3(T_LEN / 8, B_SZ), 256, 0, stream>>>(
      xz, conv_w, conv_b, W_xproj, u, BC);
  // 5-7. chunked scan
  scan1_kernel<<<dim3(D_INNER / 256, B_SZ, NCHUNK), 256, 0, stream>>>(
      dy, u, BC, A_log, hEnd, sumD);
  scan2_kernel<<<(B_SZ * D_INNER * D_STATE) / 256, 256, 0, stream>>>(A_log,
                                                                     hEnd, sumD);
  scan3_kernel<<<dim3(D_INNER / 256, B_SZ, NCHUNK), 256, 0, stream>>>(
      dy, u, BC, A_log, hEnd, xz, D_param, yb);
  // 8. out = y @ W_out
  gemm_mfma<EPI_NONE><<<dim3(D_MODEL / 128, ROWS / 128), 256, 0, stream>>>(
      yb, WoT, out, ROWS, D_MODEL, D_INNER, nullptr, nullptr, nullptr);
}